// Round 1
// baseline (1250.650 us; speedup 1.0000x reference)
//
#include <hip/hip_runtime.h>
#include <hip/hip_bf16.h>
#include <math.h>

#define DIM 128

// ---------------- prep: sigmoid(rel) -> sig_rel ----------------
__global__ void prep_sig_kernel(const float* __restrict__ rel,
                                float* __restrict__ sig_rel, int n) {
    int i = blockIdx.x * blockDim.x + threadIdx.x;
    if (i < n) {
        float x = rel[i];
        sig_rel[i] = 1.0f / (1.0f + expf(-x));
    }
}

// ---------------- prep: transpose the three 128x128 W matrices ----------------
// Wt[k*128 + j] = W[j*128 + k]
__global__ void prep_transpose_kernel(const float* __restrict__ Ws,
                                      const float* __restrict__ Wn,
                                      const float* __restrict__ Wr,
                                      float* __restrict__ Ts,
                                      float* __restrict__ Tn,
                                      float* __restrict__ Tr) {
    int id = blockIdx.x * blockDim.x + threadIdx.x;  // 0 .. 3*16384-1
    if (id >= 3 * DIM * DIM) return;
    int m   = id / (DIM * DIM);
    int lid = id - m * (DIM * DIM);
    int k = lid >> 7;
    int j = lid & 127;
    const float* S = (m == 0) ? Ws : (m == 1) ? Wn : Wr;
    float*       D = (m == 0) ? Ts : (m == 1) ? Tn : Tr;
    D[lid] = S[j * DIM + k];
}

// ---------------- scatter: agg[dst] += ent[src] * sig_rel[type] ----------------
// 32 lanes per edge, each lane owns a float4 chunk of the 128-dim row.
__global__ __launch_bounds__(256) void scatter_kernel(
    const float* __restrict__ ent,
    const float* __restrict__ sig_rel,
    const int* __restrict__ edge_index,   // [2, E] flattened
    const int* __restrict__ edge_type,    // [E]
    float* __restrict__ agg,              // [N, 128]
    int E) {
    long long tid = (long long)blockIdx.x * blockDim.x + threadIdx.x;
    int e = (int)(tid >> 5);
    int c = (int)(tid & 31);
    if (e >= E) return;
    int src = edge_index[e];
    int dst = edge_index[E + e];
    int t   = edge_type[e];
    const float4 v = *(const float4*)&ent[(size_t)src * DIM + c * 4];
    const float4 g = *(const float4*)&sig_rel[(size_t)t * DIM + c * 4];
    float* ap = &agg[(size_t)dst * DIM + c * 4];
    unsafeAtomicAdd(ap + 0, v.x * g.x);
    unsafeAtomicAdd(ap + 1, v.y * g.y);
    unsafeAtomicAdd(ap + 2, v.z * g.z);
    unsafeAtomicAdd(ap + 3, v.w * g.w);
}

// ---------------- out_rel = rel @ W_rel^T + b_rel ----------------
__global__ __launch_bounds__(128) void relout_kernel(
    const float* __restrict__ rel,
    const float* __restrict__ Wt_rel,   // transposed [k][j]
    const float* __restrict__ b_rel,
    float* __restrict__ out_rel) {
    __shared__ float rrow[DIM];
    int b = blockIdx.x;
    int t = threadIdx.x;
    rrow[t] = rel[(size_t)b * DIM + t];
    __syncthreads();
    float acc = b_rel[t];
    #pragma unroll 8
    for (int k = 0; k < DIM; ++k) {
        acc += rrow[k] * Wt_rel[k * DIM + t];
    }
    out_rel[(size_t)b * DIM + t] = acc;
}

// ---------------- out_ent = relu(ent@Ws^T + b_s + agg@Wn^T + b_n) ----------------
// agg aliases out: each block stages its 32 rows in LDS, then overwrites in place.
#define TM 32
__global__ __launch_bounds__(256) void gemm_out_ent_kernel(
    const float* __restrict__ ent,
    const float* __restrict__ agg,       // same buffer as out
    const float* __restrict__ Wt_self,   // [k][j] transposed
    const float* __restrict__ Wt_nei,
    const float* __restrict__ b_self,
    const float* __restrict__ b_nei,
    float* __restrict__ out,
    int N) {
    __shared__ float xe[TM][DIM + 4];
    __shared__ float xa[TM][DIM + 4];
    int row0 = blockIdx.x * TM;
    int t = threadIdx.x;

    // stage 32 rows of ent and agg (32*128 floats each = 1024 float4 per array)
    #pragma unroll
    for (int i = 0; i < 4; ++i) {
        int lin = t + 256 * i;       // 0..1023
        int r   = lin >> 5;          // 0..31
        int c4  = lin & 31;          // float4 index 0..31
        int row = row0 + r;
        float4 ve = make_float4(0.f, 0.f, 0.f, 0.f);
        float4 va = make_float4(0.f, 0.f, 0.f, 0.f);
        if (row < N) {
            ve = *(const float4*)&ent[(size_t)row * DIM + c4 * 4];
            va = *(const float4*)&agg[(size_t)row * DIM + c4 * 4];
        }
        *(float4*)&xe[r][c4 * 4] = ve;
        *(float4*)&xa[r][c4 * 4] = va;
    }
    __syncthreads();

    int colg = t & 31;      // 32 column groups of 4 cols
    int rowg = t >> 5;      // 8 row groups of 4 rows
    int col   = colg * 4;
    int rbase = rowg * 4;

    float acc[4][4];
    #pragma unroll
    for (int c = 0; c < 4; ++c) {
        float bias = b_self[col + c] + b_nei[col + c];
        #pragma unroll
        for (int r = 0; r < 4; ++r) acc[r][c] = bias;
    }

    for (int k = 0; k < DIM; k += 4) {
        float4 ws[4], wn[4];
        #pragma unroll
        for (int kk = 0; kk < 4; ++kk) {
            ws[kk] = *(const float4*)&Wt_self[(k + kk) * DIM + col];
            wn[kk] = *(const float4*)&Wt_nei[(k + kk) * DIM + col];
        }
        #pragma unroll
        for (int r = 0; r < 4; ++r) {
            float4 e4 = *(const float4*)&xe[rbase + r][k];
            float4 a4 = *(const float4*)&xa[rbase + r][k];
            float ev[4] = {e4.x, e4.y, e4.z, e4.w};
            float av[4] = {a4.x, a4.y, a4.z, a4.w};
            float wsx[4][4] = {
                {ws[0].x, ws[0].y, ws[0].z, ws[0].w},
                {ws[1].x, ws[1].y, ws[1].z, ws[1].w},
                {ws[2].x, ws[2].y, ws[2].z, ws[2].w},
                {ws[3].x, ws[3].y, ws[3].z, ws[3].w}};
            float wnx[4][4] = {
                {wn[0].x, wn[0].y, wn[0].z, wn[0].w},
                {wn[1].x, wn[1].y, wn[1].z, wn[1].w},
                {wn[2].x, wn[2].y, wn[2].z, wn[2].w},
                {wn[3].x, wn[3].y, wn[3].z, wn[3].w}};
            #pragma unroll
            for (int kk = 0; kk < 4; ++kk) {
                #pragma unroll
                for (int c = 0; c < 4; ++c) {
                    acc[r][c] += ev[kk] * wsx[kk][c] + av[kk] * wnx[kk][c];
                }
            }
        }
    }

    #pragma unroll
    for (int r = 0; r < 4; ++r) {
        int row = row0 + rbase + r;
        if (row < N) {
            float4 o;
            o.x = fmaxf(acc[r][0], 0.f);
            o.y = fmaxf(acc[r][1], 0.f);
            o.z = fmaxf(acc[r][2], 0.f);
            o.w = fmaxf(acc[r][3], 0.f);
            *(float4*)&out[(size_t)row * DIM + col] = o;
        }
    }
}

extern "C" void kernel_launch(void* const* d_in, const int* in_sizes, int n_in,
                              void* d_out, int out_size, void* d_ws, size_t ws_size,
                              hipStream_t stream) {
    const float* ent        = (const float*)d_in[0];
    const float* rel        = (const float*)d_in[1];
    const int*   edge_index = (const int*)d_in[2];
    const int*   edge_type  = (const int*)d_in[3];
    const float* W_self     = (const float*)d_in[4];
    const float* b_self     = (const float*)d_in[5];
    const float* W_nei      = (const float*)d_in[6];
    const float* b_nei      = (const float*)d_in[7];
    const float* W_rel      = (const float*)d_in[8];
    const float* b_rel      = (const float*)d_in[9];

    const int N = in_sizes[0] / DIM;   // 100000
    const int R = in_sizes[1] / DIM;   // 500
    const int E = in_sizes[3];         // 600000

    float* out     = (float*)d_out;
    float* agg     = out;                          // out_ent region doubles as agg
    float* out_rel = out + (size_t)N * DIM;

    float* ws      = (float*)d_ws;
    float* sig_rel = ws;                           // R*128
    float* Wt_self = sig_rel + (size_t)R * DIM;    // 16384
    float* Wt_nei  = Wt_self + DIM * DIM;
    float* Wt_rel  = Wt_nei + DIM * DIM;

    // 1. zero the agg accumulator (= out_ent region of d_out)
    hipMemsetAsync(agg, 0, (size_t)N * DIM * sizeof(float), stream);

    // 2. sigmoid(rel)
    {
        int n = R * DIM;
        prep_sig_kernel<<<(n + 255) / 256, 256, 0, stream>>>(rel, sig_rel, n);
    }

    // 3. transpose W_self, W_nei, W_rel
    {
        int n = 3 * DIM * DIM;
        prep_transpose_kernel<<<(n + 255) / 256, 256, 0, stream>>>(
            W_self, W_nei, W_rel, Wt_self, Wt_nei, Wt_rel);
    }

    // 4. scatter-add gated messages into agg
    {
        long long threads = (long long)E * 32;
        int blocks = (int)((threads + 255) / 256);
        scatter_kernel<<<blocks, 256, 0, stream>>>(ent, sig_rel, edge_index,
                                                   edge_type, agg, E);
    }

    // 5. out_rel = rel @ W_rel^T + b_rel
    relout_kernel<<<R, DIM, 0, stream>>>(rel, Wt_rel, b_rel, out_rel);

    // 6. out_ent = relu(ent@W_self^T + b_self + agg@W_nei^T + b_nei), in-place over agg
    {
        int blocks = (N + TM - 1) / TM;
        gemm_out_ent_kernel<<<blocks, 256, 0, stream>>>(
            ent, agg, Wt_self, Wt_nei, b_self, b_nei, out, N);
    }
}

// Round 2
// 402.872 us; speedup vs baseline: 3.1043x; 3.1043x over previous
//
#include <hip/hip_runtime.h>
#include <hip/hip_bf16.h>
#include <math.h>

#define DIM 128

// ---------------- prep: sigmoid(rel) -> sig_rel ----------------
__global__ void prep_sig_kernel(const float* __restrict__ rel,
                                float* __restrict__ sig_rel, int n) {
    int i = blockIdx.x * blockDim.x + threadIdx.x;
    if (i < n) {
        float x = rel[i];
        sig_rel[i] = 1.0f / (1.0f + expf(-x));
    }
}

// ---------------- prep: transpose the three 128x128 W matrices ----------------
__global__ void prep_transpose_kernel(const float* __restrict__ Ws,
                                      const float* __restrict__ Wn,
                                      const float* __restrict__ Wr,
                                      float* __restrict__ Ts,
                                      float* __restrict__ Tn,
                                      float* __restrict__ Tr) {
    int id = blockIdx.x * blockDim.x + threadIdx.x;  // 0 .. 3*16384-1
    if (id >= 3 * DIM * DIM) return;
    int m   = id / (DIM * DIM);
    int lid = id - m * (DIM * DIM);
    int k = lid >> 7;
    int j = lid & 127;
    const float* S = (m == 0) ? Ws : (m == 1) ? Wn : Wr;
    float*       D = (m == 0) ? Ts : (m == 1) ? Tn : Tr;
    D[lid] = S[j * DIM + k];
}

// ---------------- CSR build: histogram of dst ----------------
__global__ void hist_kernel(const int* __restrict__ edge_index,
                            int* __restrict__ counts, int E) {
    int e = blockIdx.x * blockDim.x + threadIdx.x;
    if (e < E) atomicAdd(&counts[edge_index[E + e]], 1);
}

// ---------------- exclusive scan over N counts (3-pass) ----------------
#define SCAN_TPB 256
#define SCAN_IPT 4
#define SCAN_IPB 1024   // items per block

__global__ void scan_pass1(int* __restrict__ data,      // in-place counts->local excl scan
                           int* __restrict__ blockSums, int N) {
    __shared__ int ts[SCAN_TPB];
    int t = threadIdx.x;
    int base = blockIdx.x * SCAN_IPB + t * SCAN_IPT;
    int v[SCAN_IPT];
    int s = 0;
    #pragma unroll
    for (int i = 0; i < SCAN_IPT; ++i) {
        int idx = base + i;
        v[i] = (idx < N) ? data[idx] : 0;
        s += v[i];
    }
    ts[t] = s;
    __syncthreads();
    // Hillis-Steele inclusive scan over 256 thread sums
    for (int off = 1; off < SCAN_TPB; off <<= 1) {
        int x = (t >= off) ? ts[t - off] : 0;
        __syncthreads();
        ts[t] += x;
        __syncthreads();
    }
    int excl = ts[t] - s;
    #pragma unroll
    for (int i = 0; i < SCAN_IPT; ++i) {
        int idx = base + i;
        if (idx < N) data[idx] = excl;
        excl += v[i];
    }
    if (t == SCAN_TPB - 1) blockSums[blockIdx.x] = ts[t];
}

__global__ void scan_pass2(int* __restrict__ blockSums, int nb) {
    if (threadIdx.x == 0 && blockIdx.x == 0) {
        int run = 0;
        for (int i = 0; i < nb; ++i) {
            int v = blockSums[i];
            blockSums[i] = run;
            run += v;
        }
    }
}

__global__ void scan_pass3(int* __restrict__ offs, const int* __restrict__ blockSums,
                           int* __restrict__ cursor, int N, int E) {
    int i = blockIdx.x * blockDim.x + threadIdx.x;
    if (i < N) {
        int o = offs[i] + blockSums[i >> 10];   // SCAN_IPB = 1024
        offs[i] = o;
        cursor[i] = o;
    }
    if (i == 0) offs[N] = E;
}

// ---------------- scatter edge ids into CSR order ----------------
__global__ void scatter_ids_kernel(const int* __restrict__ edge_index,
                                   const int* __restrict__ edge_type,
                                   int* __restrict__ cursor,
                                   int* __restrict__ ssrc,
                                   int* __restrict__ stype, int E) {
    int e = blockIdx.x * blockDim.x + threadIdx.x;
    if (e >= E) return;
    int dst = edge_index[E + e];
    int p = atomicAdd(&cursor[dst], 1);
    ssrc[p]  = edge_index[e];
    stype[p] = edge_type[e];
}

// ---------------- atomic-free segmented aggregation: 1 wave / node ----------------
__global__ __launch_bounds__(256) void aggregate_kernel(
    const float* __restrict__ ent,
    const float* __restrict__ sig_rel,
    const int* __restrict__ offs,
    const int* __restrict__ ssrc,
    const int* __restrict__ stype,
    float* __restrict__ agg, int N) {
    int wid  = (int)((blockIdx.x * (long long)blockDim.x + threadIdx.x) >> 6);
    int lane = threadIdx.x & 63;
    if (wid >= N) return;
    int beg = offs[wid], end = offs[wid + 1];
    float2 acc = make_float2(0.f, 0.f);
    for (int e = beg; e < end; ++e) {
        int s = ssrc[e];
        int t = stype[e];
        float2 v = *(const float2*)&ent[(size_t)s * DIM + lane * 2];
        float2 g = *(const float2*)&sig_rel[(size_t)t * DIM + lane * 2];
        acc.x += v.x * g.x;
        acc.y += v.y * g.y;
    }
    *(float2*)&agg[(size_t)wid * DIM + lane * 2] = acc;
}

// ---------------- out_rel = rel @ W_rel^T + b_rel ----------------
__global__ __launch_bounds__(128) void relout_kernel(
    const float* __restrict__ rel,
    const float* __restrict__ Wt_rel,
    const float* __restrict__ b_rel,
    float* __restrict__ out_rel) {
    __shared__ float rrow[DIM];
    int b = blockIdx.x;
    int t = threadIdx.x;
    rrow[t] = rel[(size_t)b * DIM + t];
    __syncthreads();
    float acc = b_rel[t];
    #pragma unroll 8
    for (int k = 0; k < DIM; ++k) {
        acc += rrow[k] * Wt_rel[k * DIM + t];
    }
    out_rel[(size_t)b * DIM + t] = acc;
}

// ---------------- out_ent = relu(ent@Ws^T + b_s + agg@Wn^T + b_n) ----------------
#define TM 32
__global__ __launch_bounds__(256) void gemm_out_ent_kernel(
    const float* __restrict__ ent,
    const float* __restrict__ agg,       // same buffer as out
    const float* __restrict__ Wt_self,
    const float* __restrict__ Wt_nei,
    const float* __restrict__ b_self,
    const float* __restrict__ b_nei,
    float* __restrict__ out,
    int N) {
    __shared__ float xe[TM][DIM + 4];
    __shared__ float xa[TM][DIM + 4];
    int row0 = blockIdx.x * TM;
    int t = threadIdx.x;

    #pragma unroll
    for (int i = 0; i < 4; ++i) {
        int lin = t + 256 * i;
        int r   = lin >> 5;
        int c4  = lin & 31;
        int row = row0 + r;
        float4 ve = make_float4(0.f, 0.f, 0.f, 0.f);
        float4 va = make_float4(0.f, 0.f, 0.f, 0.f);
        if (row < N) {
            ve = *(const float4*)&ent[(size_t)row * DIM + c4 * 4];
            va = *(const float4*)&agg[(size_t)row * DIM + c4 * 4];
        }
        *(float4*)&xe[r][c4 * 4] = ve;
        *(float4*)&xa[r][c4 * 4] = va;
    }
    __syncthreads();

    int colg = t & 31;
    int rowg = t >> 5;
    int col   = colg * 4;
    int rbase = rowg * 4;

    float acc[4][4];
    #pragma unroll
    for (int c = 0; c < 4; ++c) {
        float bias = b_self[col + c] + b_nei[col + c];
        #pragma unroll
        for (int r = 0; r < 4; ++r) acc[r][c] = bias;
    }

    for (int k = 0; k < DIM; k += 4) {
        float4 ws[4], wn[4];
        #pragma unroll
        for (int kk = 0; kk < 4; ++kk) {
            ws[kk] = *(const float4*)&Wt_self[(k + kk) * DIM + col];
            wn[kk] = *(const float4*)&Wt_nei[(k + kk) * DIM + col];
        }
        #pragma unroll
        for (int r = 0; r < 4; ++r) {
            float4 e4 = *(const float4*)&xe[rbase + r][k];
            float4 a4 = *(const float4*)&xa[rbase + r][k];
            float ev[4] = {e4.x, e4.y, e4.z, e4.w};
            float av[4] = {a4.x, a4.y, a4.z, a4.w};
            float wsx[4][4] = {
                {ws[0].x, ws[0].y, ws[0].z, ws[0].w},
                {ws[1].x, ws[1].y, ws[1].z, ws[1].w},
                {ws[2].x, ws[2].y, ws[2].z, ws[2].w},
                {ws[3].x, ws[3].y, ws[3].z, ws[3].w}};
            float wnx[4][4] = {
                {wn[0].x, wn[0].y, wn[0].z, wn[0].w},
                {wn[1].x, wn[1].y, wn[1].z, wn[1].w},
                {wn[2].x, wn[2].y, wn[2].z, wn[2].w},
                {wn[3].x, wn[3].y, wn[3].z, wn[3].w}};
            #pragma unroll
            for (int kk = 0; kk < 4; ++kk) {
                #pragma unroll
                for (int c = 0; c < 4; ++c) {
                    acc[r][c] += ev[kk] * wsx[kk][c] + av[kk] * wnx[kk][c];
                }
            }
        }
    }

    #pragma unroll
    for (int r = 0; r < 4; ++r) {
        int row = row0 + rbase + r;
        if (row < N) {
            float4 o;
            o.x = fmaxf(acc[r][0], 0.f);
            o.y = fmaxf(acc[r][1], 0.f);
            o.z = fmaxf(acc[r][2], 0.f);
            o.w = fmaxf(acc[r][3], 0.f);
            *(float4*)&out[(size_t)row * DIM + col] = o;
        }
    }
}

extern "C" void kernel_launch(void* const* d_in, const int* in_sizes, int n_in,
                              void* d_out, int out_size, void* d_ws, size_t ws_size,
                              hipStream_t stream) {
    const float* ent        = (const float*)d_in[0];
    const float* rel        = (const float*)d_in[1];
    const int*   edge_index = (const int*)d_in[2];
    const int*   edge_type  = (const int*)d_in[3];
    const float* W_self     = (const float*)d_in[4];
    const float* b_self     = (const float*)d_in[5];
    const float* W_nei      = (const float*)d_in[6];
    const float* b_nei      = (const float*)d_in[7];
    const float* W_rel      = (const float*)d_in[8];
    const float* b_rel      = (const float*)d_in[9];

    const int N = in_sizes[0] / DIM;   // 100000
    const int R = in_sizes[1] / DIM;   // 500
    const int E = in_sizes[3];         // 600000

    float* out     = (float*)d_out;
    float* agg     = out;                          // out_ent region doubles as agg
    float* out_rel = out + (size_t)N * DIM;

    // ---- workspace layout ----
    float* ws      = (float*)d_ws;
    float* sig_rel = ws;                           // R*DIM floats
    float* Wt_self = sig_rel + (size_t)R * DIM;
    float* Wt_nei  = Wt_self + DIM * DIM;
    float* Wt_rel  = Wt_nei + DIM * DIM;
    int*   offs    = (int*)(Wt_rel + DIM * DIM);   // N+8 ints (counts -> offsets)
    int*   cursor  = offs + (N + 8);               // N+8 ints
    int*   bsums   = cursor + (N + 8);             // 128 ints
    int*   ssrc    = bsums + 128;                  // E ints
    int*   stype   = ssrc + E;                     // E ints

    const int scanBlocks = (N + SCAN_IPB - 1) / SCAN_IPB;   // 98

    // 1. sigmoid(rel)
    {
        int n = R * DIM;
        prep_sig_kernel<<<(n + 255) / 256, 256, 0, stream>>>(rel, sig_rel, n);
    }
    // 2. transpose weights
    {
        int n = 3 * DIM * DIM;
        prep_transpose_kernel<<<(n + 255) / 256, 256, 0, stream>>>(
            W_self, W_nei, W_rel, Wt_self, Wt_nei, Wt_rel);
    }
    // 3. CSR build: histogram -> scan -> id scatter
    hipMemsetAsync(offs, 0, (size_t)(N + 1) * sizeof(int), stream);
    hist_kernel<<<(E + 255) / 256, 256, 0, stream>>>(edge_index, offs, E);
    scan_pass1<<<scanBlocks, SCAN_TPB, 0, stream>>>(offs, bsums, N);
    scan_pass2<<<1, 64, 0, stream>>>(bsums, scanBlocks);
    scan_pass3<<<(N + 255) / 256, 256, 0, stream>>>(offs, bsums, cursor, N, E);
    scatter_ids_kernel<<<(E + 255) / 256, 256, 0, stream>>>(
        edge_index, edge_type, cursor, ssrc, stype, E);

    // 4. atomic-free segmented aggregation (writes every row -> no memset of agg)
    {
        long long threads = (long long)N * 64;
        int blocks = (int)((threads + 255) / 256);
        aggregate_kernel<<<blocks, 256, 0, stream>>>(ent, sig_rel, offs, ssrc,
                                                     stype, agg, N);
    }

    // 5. out_rel = rel @ W_rel^T + b_rel
    relout_kernel<<<R, DIM, 0, stream>>>(rel, Wt_rel, b_rel, out_rel);

    // 6. out_ent = relu(ent@W_self^T + b_self + agg@W_nei^T + b_nei)
    {
        int blocks = (N + TM - 1) / TM;
        gemm_out_ent_kernel<<<blocks, 256, 0, stream>>>(
            ent, agg, Wt_self, Wt_nei, b_self, b_nei, out, N);
    }
}

// Round 5
// 299.557 us; speedup vs baseline: 4.1750x; 1.3449x over previous
//
#include <hip/hip_runtime.h>
#include <hip/hip_bf16.h>
#include <math.h>

#define DIM 128

typedef __bf16 bf8 __attribute__((ext_vector_type(8)));
typedef float f4 __attribute__((ext_vector_type(4)));

struct __align__(8) bf16x4 { __hip_bfloat162 a, b; };

// ---------------- prep: sigmoid(rel) -> sig_rel (fp32) ----------------
__global__ void prep_sig_kernel(const float* __restrict__ rel,
                                float* __restrict__ sig_rel, int n) {
    int i = blockIdx.x * blockDim.x + threadIdx.x;
    if (i < n) {
        float x = rel[i];
        sig_rel[i] = 1.0f / (1.0f + expf(-x));
    }
}

// ---------------- prep: Wcat[j][k'] bf16, k'<128 -> W_self[j][k'], else W_nei ----------------
__global__ void prep_wcat_kernel(const float* __restrict__ Ws,
                                 const float* __restrict__ Wn,
                                 __hip_bfloat16* __restrict__ Wcat) {
    int idx = blockIdx.x * blockDim.x + threadIdx.x;  // 0..8191, 4 elems each
    if (idx >= DIM * 256 / 4) return;
    int j  = idx >> 6;        // row 0..127
    int kq = idx & 63;        // 4-elem group 0..63
    int k0 = kq * 4;
    const float* src = (k0 < DIM) ? &Ws[j * DIM + k0] : &Wn[j * DIM + (k0 - DIM)];
    float4 v = *(const float4*)src;
    bf16x4 o;
    o.a.x = __float2bfloat16(v.x);
    o.a.y = __float2bfloat16(v.y);
    o.b.x = __float2bfloat16(v.z);
    o.b.y = __float2bfloat16(v.w);
    *(bf16x4*)&Wcat[(size_t)j * 256 + k0] = o;
}

// ---------------- prep: transpose W_rel (fp32, tiny) ----------------
__global__ void prep_wrelT_kernel(const float* __restrict__ Wr,
                                  float* __restrict__ Tr) {
    int id = blockIdx.x * blockDim.x + threadIdx.x;
    if (id >= DIM * DIM) return;
    int k = id >> 7;
    int j = id & 127;
    Tr[id] = Wr[j * DIM + k];
}

// ---------------- conv: ent fp32 -> xcat cols 0..127 bf16 ----------------
__global__ __launch_bounds__(256) void conv_ent_kernel(
    const float* __restrict__ ent,
    __hip_bfloat16* __restrict__ xcat, int N) {
    long long tid = (long long)blockIdx.x * blockDim.x + threadIdx.x;
    int row = (int)(tid >> 5);
    int q   = (int)(tid & 31);       // 4-elem group
    if (row >= N) return;
    float4 v = *(const float4*)&ent[(size_t)row * DIM + q * 4];
    bf16x4 o;
    o.a.x = __float2bfloat16(v.x);
    o.a.y = __float2bfloat16(v.y);
    o.b.x = __float2bfloat16(v.z);
    o.b.y = __float2bfloat16(v.w);
    *(bf16x4*)&xcat[(size_t)row * 256 + q * 4] = o;
}

// ---------------- CSR build: histogram of dst ----------------
__global__ void hist_kernel(const int* __restrict__ edge_index,
                            int* __restrict__ counts, int E) {
    int e = blockIdx.x * blockDim.x + threadIdx.x;
    if (e < E) atomicAdd(&counts[edge_index[E + e]], 1);
}

// ---------------- exclusive scan over N counts (3-pass) ----------------
#define SCAN_TPB 256
#define SCAN_IPT 4
#define SCAN_IPB 1024

__global__ void scan_pass1(int* __restrict__ data,
                           int* __restrict__ blockSums, int N) {
    __shared__ int ts[SCAN_TPB];
    int t = threadIdx.x;
    int base = blockIdx.x * SCAN_IPB + t * SCAN_IPT;
    int v[SCAN_IPT];
    int s = 0;
    #pragma unroll
    for (int i = 0; i < SCAN_IPT; ++i) {
        int idx = base + i;
        v[i] = (idx < N) ? data[idx] : 0;
        s += v[i];
    }
    ts[t] = s;
    __syncthreads();
    for (int off = 1; off < SCAN_TPB; off <<= 1) {
        int x = (t >= off) ? ts[t - off] : 0;
        __syncthreads();
        ts[t] += x;
        __syncthreads();
    }
    int excl = ts[t] - s;
    #pragma unroll
    for (int i = 0; i < SCAN_IPT; ++i) {
        int idx = base + i;
        if (idx < N) data[idx] = excl;
        excl += v[i];
    }
    if (t == SCAN_TPB - 1) blockSums[blockIdx.x] = ts[t];
}

__global__ void scan_pass2(int* __restrict__ blockSums, int nb) {
    if (threadIdx.x == 0 && blockIdx.x == 0) {
        int run = 0;
        for (int i = 0; i < nb; ++i) {
            int v = blockSums[i];
            blockSums[i] = run;
            run += v;
        }
    }
}

__global__ void scan_pass3(int* __restrict__ offs, const int* __restrict__ blockSums,
                           int* __restrict__ cursor, int N, int E) {
    int i = blockIdx.x * blockDim.x + threadIdx.x;
    if (i < N) {
        int o = offs[i] + blockSums[i >> 10];
        offs[i] = o;
        cursor[i] = o;
    }
    if (i == 0) offs[N] = E;
}

// ---------------- scatter (src,type) pairs into CSR order ----------------
__global__ void scatter_ids_kernel(const int* __restrict__ edge_index,
                                   const int* __restrict__ edge_type,
                                   int* __restrict__ cursor,
                                   int2* __restrict__ spair, int E) {
    int e = blockIdx.x * blockDim.x + threadIdx.x;
    if (e >= E) return;
    int dst = edge_index[E + e];
    int p = atomicAdd(&cursor[dst], 1);
    spair[p] = make_int2(edge_index[e], edge_type[e]);
}

// ---------------- atomic-free aggregation: 1 wave / node, bf16 in/out ----------------
// gathers ent rows from xcat cols 0..127 (cache lines 0-1 of each row), writes
// agg into xcat cols 128..255 (lines 2-3) -> no false sharing.
__global__ __launch_bounds__(256) void aggregate_kernel(
    const __hip_bfloat16* __restrict__ xcat,
    const float* __restrict__ sig_rel,
    const int* __restrict__ offs,
    const int2* __restrict__ spair,
    __hip_bfloat16* __restrict__ xcat_w, int N) {
    int wid  = (int)((blockIdx.x * (long long)blockDim.x + threadIdx.x) >> 6);
    int lane = threadIdx.x & 63;
    if (wid >= N) return;
    int beg = offs[wid], end = offs[wid + 1];
    float ax = 0.f, ay = 0.f;
    for (int e = beg; e < end; ++e) {
        int2 st = spair[e];
        __hip_bfloat162 v = *(const __hip_bfloat162*)&xcat[(size_t)st.x * 256 + lane * 2];
        float2 g = *(const float2*)&sig_rel[(size_t)st.y * DIM + lane * 2];
        ax += __bfloat162float(v.x) * g.x;
        ay += __bfloat162float(v.y) * g.y;
    }
    __hip_bfloat162 o;
    o.x = __float2bfloat16(ax);
    o.y = __float2bfloat16(ay);
    *(__hip_bfloat162*)&xcat_w[(size_t)wid * 256 + 128 + lane * 2] = o;
}

// ---------------- out_rel = rel @ W_rel^T + b_rel (fp32, tiny) ----------------
__global__ __launch_bounds__(128) void relout_kernel(
    const float* __restrict__ rel,
    const float* __restrict__ Wt_rel,
    const float* __restrict__ b_rel,
    float* __restrict__ out_rel) {
    __shared__ float rrow[DIM];
    int b = blockIdx.x;
    int t = threadIdx.x;
    rrow[t] = rel[(size_t)b * DIM + t];
    __syncthreads();
    float acc = b_rel[t];
    #pragma unroll 8
    for (int k = 0; k < DIM; ++k) {
        acc += rrow[k] * Wt_rel[k * DIM + t];
    }
    out_rel[(size_t)b * DIM + t] = acc;
}

// ---------------- out_ent = relu(xcat @ Wcat^T + bias) via bf16 MFMA ----------------
// xcat is IN-PLACE in the out buffer; each wave reads only its own 32 rows
// before its epilogue overwrites them.
__global__ __launch_bounds__(256) void gemm_mfma_kernel(
    const __hip_bfloat16* __restrict__ xcat,   // [N][256] bf16 (aliases out)
    const __hip_bfloat16* __restrict__ Wcat,   // [128][256] bf16
    const float* __restrict__ b_self,
    const float* __restrict__ b_nei,
    float* __restrict__ out, int N) {
    __shared__ __hip_bfloat16 Bs[128][264];    // +8 pad -> conflict-free b128 reads

    int t    = threadIdx.x;
    int wave = t >> 6;
    int lane = t & 63;
    int quad = lane >> 4;
    int r16  = lane & 15;

    // stage Wcat -> LDS: thread copies a half-row = 128 bf16 = 256 B = 16 float4
    {
        int r = t >> 1, h = t & 1;
        const float4* src = (const float4*)&Wcat[(size_t)r * 256 + h * 128];
        #pragma unroll
        for (int i = 0; i < 16; ++i) {
            *(float4*)&Bs[r][h * 128 + i * 8] = src[i];
        }
    }
    __syncthreads();

    int row0 = blockIdx.x * 128 + wave * 32;

    // load all A-frags up front (2 row-tiles x 8 k-steps)
    bf8 a[2][8];
    #pragma unroll
    for (int rt = 0; rt < 2; ++rt) {
        int m = row0 + rt * 16 + r16;
        if (m > N - 1) m = N - 1;               // clamp (guarded store below)
        const __hip_bfloat16* ap = &xcat[(size_t)m * 256 + quad * 8];
        #pragma unroll
        for (int ks = 0; ks < 8; ++ks) {
            a[rt][ks] = *(const bf8*)(ap + ks * 32);
        }
    }

    f4 acc[2][8];
    #pragma unroll
    for (int rt = 0; rt < 2; ++rt)
        #pragma unroll
        for (int ct = 0; ct < 8; ++ct)
            acc[rt][ct] = (f4){0.f, 0.f, 0.f, 0.f};

    #pragma unroll
    for (int ks = 0; ks < 8; ++ks) {
        #pragma unroll
        for (int ct = 0; ct < 8; ++ct) {
            bf8 b = *(const bf8*)&Bs[ct * 16 + r16][ks * 32 + quad * 8];
            acc[0][ct] = __builtin_amdgcn_mfma_f32_16x16x32_bf16(a[0][ks], b, acc[0][ct], 0, 0, 0);
            acc[1][ct] = __builtin_amdgcn_mfma_f32_16x16x32_bf16(a[1][ks], b, acc[1][ct], 0, 0, 0);
        }
    }

    // epilogue: +bias, relu, store fp32 (overwrites this wave's xcat rows)
    float bias[8];
    #pragma unroll
    for (int ct = 0; ct < 8; ++ct) {
        int col = ct * 16 + r16;
        bias[ct] = b_self[col] + b_nei[col];
    }
    #pragma unroll
    for (int rt = 0; rt < 2; ++rt) {
        #pragma unroll
        for (int i = 0; i < 4; ++i) {
            int m = row0 + rt * 16 + quad * 4 + i;
            if (m < N) {
                #pragma unroll
                for (int ct = 0; ct < 8; ++ct) {
                    float v = acc[rt][ct][i] + bias[ct];
                    out[(size_t)m * DIM + ct * 16 + r16] = fmaxf(v, 0.f);
                }
            }
        }
    }
}

extern "C" void kernel_launch(void* const* d_in, const int* in_sizes, int n_in,
                              void* d_out, int out_size, void* d_ws, size_t ws_size,
                              hipStream_t stream) {
    const float* ent        = (const float*)d_in[0];
    const float* rel        = (const float*)d_in[1];
    const int*   edge_index = (const int*)d_in[2];
    const int*   edge_type  = (const int*)d_in[3];
    const float* W_self     = (const float*)d_in[4];
    const float* b_self     = (const float*)d_in[5];
    const float* W_nei      = (const float*)d_in[6];
    const float* b_nei      = (const float*)d_in[7];
    const float* W_rel      = (const float*)d_in[8];
    const float* b_rel      = (const float*)d_in[9];

    const int N = in_sizes[0] / DIM;   // 100000
    const int R = in_sizes[1] / DIM;   // 500
    const int E = in_sizes[3];         // 600000

    float* out     = (float*)d_out;
    float* out_rel = out + (size_t)N * DIM;
    __hip_bfloat16* xcat = (__hip_bfloat16*)d_out;   // [N][256] bf16 in-place

    // ---- workspace layout ----
    float* ws      = (float*)d_ws;
    float* sig_rel = ws;                               // R*DIM floats
    float* Wt_rel  = sig_rel + (size_t)R * DIM;        // DIM*DIM floats
    __hip_bfloat16* Wcat = (__hip_bfloat16*)(Wt_rel + DIM * DIM);  // 128*256 bf16
    int*   offs    = (int*)(Wcat + 128 * 256);         // N+8 ints
    int*   cursor  = offs + (N + 8);                   // N+8 ints
    int*   bsums   = cursor + (N + 8);                 // 128 ints
    int2*  spair   = (int2*)(bsums + 128);             // E int2

    const int scanBlocks = (N + SCAN_IPB - 1) / SCAN_IPB;

    // 1. small preps
    {
        int n = R * DIM;
        prep_sig_kernel<<<(n + 255) / 256, 256, 0, stream>>>(rel, sig_rel, n);
    }
    prep_wcat_kernel<<<(DIM * 256 / 4 + 255) / 256, 256, 0, stream>>>(W_self, W_nei, Wcat);
    prep_wrelT_kernel<<<(DIM * DIM + 255) / 256, 256, 0, stream>>>(W_rel, Wt_rel);

    // 2. ent -> xcat bf16 (cols 0..127)
    {
        long long threads = (long long)N * 32;
        conv_ent_kernel<<<(int)((threads + 255) / 256), 256, 0, stream>>>(ent, xcat, N);
    }

    // 3. CSR build
    hipMemsetAsync(offs, 0, (size_t)(N + 1) * sizeof(int), stream);
    hist_kernel<<<(E + 255) / 256, 256, 0, stream>>>(edge_index, offs, E);
    scan_pass1<<<scanBlocks, SCAN_TPB, 0, stream>>>(offs, bsums, N);
    scan_pass2<<<1, 64, 0, stream>>>(bsums, scanBlocks);
    scan_pass3<<<(N + 255) / 256, 256, 0, stream>>>(offs, bsums, cursor, N, E);
    scatter_ids_kernel<<<(E + 255) / 256, 256, 0, stream>>>(
        edge_index, edge_type, cursor, spair, E);

    // 4. aggregation -> xcat cols 128..255 (bf16)
    {
        long long threads = (long long)N * 64;
        aggregate_kernel<<<(int)((threads + 255) / 256), 256, 0, stream>>>(
            xcat, sig_rel, offs, spair, xcat, N);
    }

    // 5. out_rel
    relout_kernel<<<R, DIM, 0, stream>>>(rel, Wt_rel, b_rel, out_rel);

    // 6. fused bf16 MFMA GEMM, in-place over xcat
    {
        int blocks = (N + 127) / 128;
        gemm_mfma_kernel<<<blocks, 256, 0, stream>>>(xcat, Wcat, b_self, b_nei, out, N);
    }
}

// Round 6
// 250.316 us; speedup vs baseline: 4.9963x; 1.1967x over previous
//
#include <hip/hip_runtime.h>
#include <hip/hip_bf16.h>
#include <math.h>

#define DIM 128

typedef __bf16 bf8 __attribute__((ext_vector_type(8)));
typedef float f4 __attribute__((ext_vector_type(4)));

struct __align__(8) bf16x4 { __hip_bfloat162 a, b; };

// ---------------- merged prep: sigmoid(rel)->bf16, Wcat bf16, W_rel^T ----------------
__global__ __launch_bounds__(256) void prep_kernel(
    const float* __restrict__ rel,
    const float* __restrict__ Ws,
    const float* __restrict__ Wn,
    const float* __restrict__ Wr,
    __hip_bfloat16* __restrict__ sigb,
    __hip_bfloat16* __restrict__ Wcat,
    float* __restrict__ Wt_rel,
    int nSig, int sigBlocks) {
    int b = blockIdx.x;
    if (b < sigBlocks) {
        int i = b * 256 + threadIdx.x;
        if (i < nSig) {
            float x = rel[i];
            sigb[i] = __float2bfloat16(1.0f / (1.0f + expf(-x)));
        }
    } else if (b < sigBlocks + 32) {
        int idx = (b - sigBlocks) * 256 + threadIdx.x;   // 0..8191, 4 elems each
        int j  = idx >> 6;
        int k0 = (idx & 63) * 4;
        const float* src = (k0 < DIM) ? &Ws[j * DIM + k0] : &Wn[j * DIM + (k0 - DIM)];
        float4 v = *(const float4*)src;
        bf16x4 o;
        o.a.x = __float2bfloat16(v.x);
        o.a.y = __float2bfloat16(v.y);
        o.b.x = __float2bfloat16(v.z);
        o.b.y = __float2bfloat16(v.w);
        *(bf16x4*)&Wcat[(size_t)j * 256 + k0] = o;
    } else {
        int id = (b - sigBlocks - 32) * 256 + threadIdx.x;  // 0..16383
        int k = id >> 7;
        int j = id & 127;
        Wt_rel[id] = Wr[j * DIM + k];
    }
}

// ---------------- merged: ent fp32 -> xcat bf16 (cols 0..127)  +  dst histogram ----------------
__global__ __launch_bounds__(256) void conv_hist_kernel(
    const float* __restrict__ ent,
    __hip_bfloat16* __restrict__ xcat,
    const int* __restrict__ edge_index,
    int* __restrict__ counts,
    int N, int E, int convBlocks) {
    if ((int)blockIdx.x < convBlocks) {
        long long tid = (long long)blockIdx.x * 256 + threadIdx.x;
        int row = (int)(tid >> 5);
        int q   = (int)(tid & 31);
        if (row >= N) return;
        float4 v = *(const float4*)&ent[(size_t)row * DIM + q * 4];
        bf16x4 o;
        o.a.x = __float2bfloat16(v.x);
        o.a.y = __float2bfloat16(v.y);
        o.b.x = __float2bfloat16(v.z);
        o.b.y = __float2bfloat16(v.w);
        *(bf16x4*)&xcat[(size_t)row * 256 + q * 4] = o;
    } else {
        int e = (blockIdx.x - convBlocks) * 256 + threadIdx.x;
        if (e < E) atomicAdd(&counts[edge_index[E + e]], 1);
    }
}

// ---------------- exclusive scan over N counts (3-pass) ----------------
#define SCAN_TPB 256
#define SCAN_IPT 4
#define SCAN_IPB 1024

__global__ void scan_pass1(int* __restrict__ data,
                           int* __restrict__ blockSums, int N) {
    __shared__ int ts[SCAN_TPB];
    int t = threadIdx.x;
    int base = blockIdx.x * SCAN_IPB + t * SCAN_IPT;
    int v[SCAN_IPT];
    int s = 0;
    #pragma unroll
    for (int i = 0; i < SCAN_IPT; ++i) {
        int idx = base + i;
        v[i] = (idx < N) ? data[idx] : 0;
        s += v[i];
    }
    ts[t] = s;
    __syncthreads();
    for (int off = 1; off < SCAN_TPB; off <<= 1) {
        int x = (t >= off) ? ts[t - off] : 0;
        __syncthreads();
        ts[t] += x;
        __syncthreads();
    }
    int excl = ts[t] - s;
    #pragma unroll
    for (int i = 0; i < SCAN_IPT; ++i) {
        int idx = base + i;
        if (idx < N) data[idx] = excl;
        excl += v[i];
    }
    if (t == SCAN_TPB - 1) blockSums[blockIdx.x] = ts[t];
}

// parallel exclusive scan of <=128 block sums (1 block, 128 threads)
__global__ void scan_pass2(int* __restrict__ blockSums, int nb) {
    __shared__ int s[128];
    int t = threadIdx.x;
    int v = (t < nb) ? blockSums[t] : 0;
    s[t] = v;
    __syncthreads();
    for (int off = 1; off < 128; off <<= 1) {
        int x = (t >= off) ? s[t - off] : 0;
        __syncthreads();
        s[t] += x;
        __syncthreads();
    }
    if (t < nb) blockSums[t] = s[t] - v;   // exclusive
}

__global__ void scan_pass3(int* __restrict__ offs, const int* __restrict__ blockSums,
                           int* __restrict__ cursor, int N, int E) {
    int i = blockIdx.x * blockDim.x + threadIdx.x;
    if (i < N) {
        int o = offs[i] + blockSums[i >> 10];
        offs[i] = o;
        cursor[i] = o;
    }
    if (i == 0) offs[N] = E;
}

// ---------------- scatter packed (src | type<<17) into CSR order ----------------
__global__ void scatter_ids_kernel(const int* __restrict__ edge_index,
                                   const int* __restrict__ edge_type,
                                   int* __restrict__ cursor,
                                   unsigned* __restrict__ spack, int E) {
    int e = blockIdx.x * blockDim.x + threadIdx.x;
    if (e >= E) return;
    int dst = edge_index[E + e];
    int p = atomicAdd(&cursor[dst], 1);
    spack[p] = (unsigned)edge_index[e] | ((unsigned)edge_type[e] << 17);
}

// ---------------- atomic-free aggregation: 1 wave / node, 4x unrolled gather ----------------
__global__ __launch_bounds__(256) void aggregate_kernel(
    const __hip_bfloat16* __restrict__ xcat,
    const __hip_bfloat16* __restrict__ sigb,
    const int* __restrict__ offs,
    const unsigned* __restrict__ spack,
    __hip_bfloat16* __restrict__ xcat_w, int N) {
    int wid  = (int)((blockIdx.x * (long long)blockDim.x + threadIdx.x) >> 6);
    int lane = threadIdx.x & 63;
    if (wid >= N) return;
    int beg = offs[wid], end = offs[wid + 1];
    float ax0 = 0.f, ay0 = 0.f, ax1 = 0.f, ay1 = 0.f;
    int e = beg;
    for (; e + 4 <= end; e += 4) {
        unsigned p0 = spack[e + 0];
        unsigned p1 = spack[e + 1];
        unsigned p2 = spack[e + 2];
        unsigned p3 = spack[e + 3];
        __hip_bfloat162 v0 = *(const __hip_bfloat162*)&xcat[(size_t)(p0 & 0x1FFFFu) * 256 + lane * 2];
        __hip_bfloat162 v1 = *(const __hip_bfloat162*)&xcat[(size_t)(p1 & 0x1FFFFu) * 256 + lane * 2];
        __hip_bfloat162 v2 = *(const __hip_bfloat162*)&xcat[(size_t)(p2 & 0x1FFFFu) * 256 + lane * 2];
        __hip_bfloat162 v3 = *(const __hip_bfloat162*)&xcat[(size_t)(p3 & 0x1FFFFu) * 256 + lane * 2];
        __hip_bfloat162 g0 = *(const __hip_bfloat162*)&sigb[(size_t)(p0 >> 17) * DIM + lane * 2];
        __hip_bfloat162 g1 = *(const __hip_bfloat162*)&sigb[(size_t)(p1 >> 17) * DIM + lane * 2];
        __hip_bfloat162 g2 = *(const __hip_bfloat162*)&sigb[(size_t)(p2 >> 17) * DIM + lane * 2];
        __hip_bfloat162 g3 = *(const __hip_bfloat162*)&sigb[(size_t)(p3 >> 17) * DIM + lane * 2];
        ax0 += __bfloat162float(v0.x) * __bfloat162float(g0.x);
        ay0 += __bfloat162float(v0.y) * __bfloat162float(g0.y);
        ax1 += __bfloat162float(v1.x) * __bfloat162float(g1.x);
        ay1 += __bfloat162float(v1.y) * __bfloat162float(g1.y);
        ax0 += __bfloat162float(v2.x) * __bfloat162float(g2.x);
        ay0 += __bfloat162float(v2.y) * __bfloat162float(g2.y);
        ax1 += __bfloat162float(v3.x) * __bfloat162float(g3.x);
        ay1 += __bfloat162float(v3.y) * __bfloat162float(g3.y);
    }
    for (; e < end; ++e) {
        unsigned p = spack[e];
        __hip_bfloat162 v = *(const __hip_bfloat162*)&xcat[(size_t)(p & 0x1FFFFu) * 256 + lane * 2];
        __hip_bfloat162 g = *(const __hip_bfloat162*)&sigb[(size_t)(p >> 17) * DIM + lane * 2];
        ax0 += __bfloat162float(v.x) * __bfloat162float(g.x);
        ay0 += __bfloat162float(v.y) * __bfloat162float(g.y);
    }
    __hip_bfloat162 o;
    o.x = __float2bfloat16(ax0 + ax1);
    o.y = __float2bfloat16(ay0 + ay1);
    *(__hip_bfloat162*)&xcat_w[(size_t)wid * 256 + 128 + lane * 2] = o;
}

// ---------------- out_rel = rel @ W_rel^T + b_rel (fp32, tiny) ----------------
__global__ __launch_bounds__(128) void relout_kernel(
    const float* __restrict__ rel,
    const float* __restrict__ Wt_rel,
    const float* __restrict__ b_rel,
    float* __restrict__ out_rel) {
    __shared__ float rrow[DIM];
    int b = blockIdx.x;
    int t = threadIdx.x;
    rrow[t] = rel[(size_t)b * DIM + t];
    __syncthreads();
    float acc = b_rel[t];
    #pragma unroll 8
    for (int k = 0; k < DIM; ++k) {
        acc += rrow[k] * Wt_rel[k * DIM + t];
    }
    out_rel[(size_t)b * DIM + t] = acc;
}

// ---------------- out_ent = relu(xcat @ Wcat^T + bias) via bf16 MFMA ----------------
__global__ __launch_bounds__(256) void gemm_mfma_kernel(
    const __hip_bfloat16* __restrict__ xcat,   // [N][256] bf16 (aliases out)
    const __hip_bfloat16* __restrict__ Wcat,   // [128][256] bf16
    const float* __restrict__ b_self,
    const float* __restrict__ b_nei,
    float* __restrict__ out, int N) {
    __shared__ __hip_bfloat16 Bs[128][264];    // +8 pad; SQ_LDS_BANK_CONFLICT measured 0

    int t    = threadIdx.x;
    int wave = t >> 6;
    int lane = t & 63;
    int quad = lane >> 4;
    int r16  = lane & 15;

    // stage Wcat -> LDS: thread copies a half-row = 128 bf16 = 256 B = 16 float4
    {
        int r = t >> 1, h = t & 1;
        const float4* src = (const float4*)&Wcat[(size_t)r * 256 + h * 128];
        #pragma unroll
        for (int i = 0; i < 16; ++i) {
            *(float4*)&Bs[r][h * 128 + i * 8] = src[i];
        }
    }
    __syncthreads();

    int row0 = blockIdx.x * 128 + wave * 32;

    bf8 a[2][8];
    #pragma unroll
    for (int rt = 0; rt < 2; ++rt) {
        int m = row0 + rt * 16 + r16;
        if (m > N - 1) m = N - 1;               // clamp (store guarded below)
        const __hip_bfloat16* ap = &xcat[(size_t)m * 256 + quad * 8];
        #pragma unroll
        for (int ks = 0; ks < 8; ++ks) {
            a[rt][ks] = *(const bf8*)(ap + ks * 32);
        }
    }

    f4 acc[2][8];
    #pragma unroll
    for (int rt = 0; rt < 2; ++rt)
        #pragma unroll
        for (int ct = 0; ct < 8; ++ct)
            acc[rt][ct] = (f4){0.f, 0.f, 0.f, 0.f};

    #pragma unroll
    for (int ks = 0; ks < 8; ++ks) {
        #pragma unroll
        for (int ct = 0; ct < 8; ++ct) {
            bf8 b = *(const bf8*)&Bs[ct * 16 + r16][ks * 32 + quad * 8];
            acc[0][ct] = __builtin_amdgcn_mfma_f32_16x16x32_bf16(a[0][ks], b, acc[0][ct], 0, 0, 0);
            acc[1][ct] = __builtin_amdgcn_mfma_f32_16x16x32_bf16(a[1][ks], b, acc[1][ct], 0, 0, 0);
        }
    }

    float bias[8];
    #pragma unroll
    for (int ct = 0; ct < 8; ++ct) {
        int col = ct * 16 + r16;
        bias[ct] = b_self[col] + b_nei[col];
    }
    #pragma unroll
    for (int rt = 0; rt < 2; ++rt) {
        #pragma unroll
        for (int i = 0; i < 4; ++i) {
            int m = row0 + rt * 16 + quad * 4 + i;
            if (m < N) {
                #pragma unroll
                for (int ct = 0; ct < 8; ++ct) {
                    float v = acc[rt][ct][i] + bias[ct];
                    out[(size_t)m * DIM + ct * 16 + r16] = fmaxf(v, 0.f);
                }
            }
        }
    }
}

extern "C" void kernel_launch(void* const* d_in, const int* in_sizes, int n_in,
                              void* d_out, int out_size, void* d_ws, size_t ws_size,
                              hipStream_t stream) {
    const float* ent        = (const float*)d_in[0];
    const float* rel        = (const float*)d_in[1];
    const int*   edge_index = (const int*)d_in[2];
    const int*   edge_type  = (const int*)d_in[3];
    const float* W_self     = (const float*)d_in[4];
    const float* b_self     = (const float*)d_in[5];
    const float* W_nei      = (const float*)d_in[6];
    const float* b_nei      = (const float*)d_in[7];
    const float* W_rel      = (const float*)d_in[8];
    const float* b_rel      = (const float*)d_in[9];

    const int N = in_sizes[0] / DIM;   // 100000
    const int R = in_sizes[1] / DIM;   // 500
    const int E = in_sizes[3];         // 600000

    float* out     = (float*)d_out;
    float* out_rel = out + (size_t)N * DIM;
    __hip_bfloat16* xcat = (__hip_bfloat16*)d_out;     // [N][256] bf16 in-place

    // ---- workspace layout (16B-aligned sections) ----
    __hip_bfloat16* sigb = (__hip_bfloat16*)d_ws;                  // R*DIM bf16
    float* Wt_rel  = (float*)(sigb + (size_t)R * DIM);             // DIM*DIM fp32
    __hip_bfloat16* Wcat = (__hip_bfloat16*)(Wt_rel + DIM * DIM);  // 128*256 bf16
    int*   offs    = (int*)(Wcat + 128 * 256);         // N+8 ints
    int*   cursor  = offs + (N + 8);                   // N+8 ints
    int*   bsums   = cursor + (N + 8);                 // 128 ints
    unsigned* spack = (unsigned*)(bsums + 128);        // E u32

    const int scanBlocks = (N + SCAN_IPB - 1) / SCAN_IPB;
    const int nSig = R * DIM;
    const int sigBlocks = (nSig + 255) / 256;

    // 1. merged preps (sig bf16, Wcat bf16, W_rel^T)
    prep_kernel<<<sigBlocks + 32 + 64, 256, 0, stream>>>(
        rel, W_self, W_nei, W_rel, sigb, Wcat, Wt_rel, nSig, sigBlocks);

    // 2. zero counts, then merged conv(ent->bf16) + dst histogram
    hipMemsetAsync(offs, 0, (size_t)(N + 1) * sizeof(int), stream);
    {
        int convBlocks = (int)(((long long)N * 32 + 255) / 256);
        int histBlocks = (E + 255) / 256;
        conv_hist_kernel<<<convBlocks + histBlocks, 256, 0, stream>>>(
            ent, xcat, edge_index, offs, N, E, convBlocks);
    }

    // 3. scan -> offsets, cursors
    scan_pass1<<<scanBlocks, SCAN_TPB, 0, stream>>>(offs, bsums, N);
    scan_pass2<<<1, 128, 0, stream>>>(bsums, scanBlocks);
    scan_pass3<<<(N + 255) / 256, 256, 0, stream>>>(offs, bsums, cursor, N, E);
    scatter_ids_kernel<<<(E + 255) / 256, 256, 0, stream>>>(
        edge_index, edge_type, cursor, spack, E);

    // 4. aggregation -> xcat cols 128..255 (bf16)
    {
        long long threads = (long long)N * 64;
        aggregate_kernel<<<(int)((threads + 255) / 256), 256, 0, stream>>>(
            xcat, sigb, offs, spack, xcat, N);
    }

    // 5. out_rel
    relout_kernel<<<R, DIM, 0, stream>>>(rel, Wt_rel, b_rel, out_rel);

    // 6. fused bf16 MFMA GEMM, in-place over xcat
    {
        int blocks = (N + 127) / 128;
        gemm_mfma_kernel<<<blocks, 256, 0, stream>>>(xcat, Wcat, b_self, b_nei, out, N);
    }
}